// Round 7
// baseline (240.093 us; speedup 1.0000x reference)
//
#include <hip/hip_runtime.h>
#include <math.h>

#define CB 8
#define CNX 512
#define CNR 512
#define CD 256
#define CH 256

typedef __attribute__((ext_vector_type(8))) short short8;
typedef __attribute__((ext_vector_type(4))) float f32x4;

__device__ __forceinline__ float fast_rcp(float x) {
#if __has_builtin(__builtin_amdgcn_rcpf)
  return __builtin_amdgcn_rcpf(x);
#else
  return 1.0f / x;
#endif
}
__device__ __forceinline__ float fast_exp2(float x) {
#if __has_builtin(__builtin_amdgcn_exp2f)
  return __builtin_amdgcn_exp2f(x);
#else
  return exp2f(x);
#endif
}

// Split a float into bf16 hi (truncation) + bf16 lo (residual, truncated),
// packing 8 consecutive k-values into uint4 hi and uint4 lo, store to LDS.
__device__ __forceinline__ void cvt_store(unsigned short* dstH,
                                          unsigned short* dstL,
                                          float4 v0, float4 v1) {
  unsigned u0x = __float_as_uint(v0.x), u0y = __float_as_uint(v0.y);
  unsigned u0z = __float_as_uint(v0.z), u0w = __float_as_uint(v0.w);
  unsigned u1x = __float_as_uint(v1.x), u1y = __float_as_uint(v1.y);
  unsigned u1z = __float_as_uint(v1.z), u1w = __float_as_uint(v1.w);
  uint4 H;
  H.x = (u0x >> 16) | (u0y & 0xFFFF0000u);
  H.y = (u0z >> 16) | (u0w & 0xFFFF0000u);
  H.z = (u1x >> 16) | (u1y & 0xFFFF0000u);
  H.w = (u1z >> 16) | (u1w & 0xFFFF0000u);
  float r0x = v0.x - __uint_as_float(u0x & 0xFFFF0000u);
  float r0y = v0.y - __uint_as_float(u0y & 0xFFFF0000u);
  float r0z = v0.z - __uint_as_float(u0z & 0xFFFF0000u);
  float r0w = v0.w - __uint_as_float(u0w & 0xFFFF0000u);
  float r1x = v1.x - __uint_as_float(u1x & 0xFFFF0000u);
  float r1y = v1.y - __uint_as_float(u1y & 0xFFFF0000u);
  float r1z = v1.z - __uint_as_float(u1z & 0xFFFF0000u);
  float r1w = v1.w - __uint_as_float(u1w & 0xFFFF0000u);
  uint4 L;
  L.x = (__float_as_uint(r0x) >> 16) | (__float_as_uint(r0y) & 0xFFFF0000u);
  L.y = (__float_as_uint(r0z) >> 16) | (__float_as_uint(r0w) & 0xFFFF0000u);
  L.z = (__float_as_uint(r1x) >> 16) | (__float_as_uint(r1y) & 0xFFFF0000u);
  L.w = (__float_as_uint(r1z) >> 16) | (__float_as_uint(r1w) & 0xFFFF0000u);
  *(uint4*)dstH = H;
  *(uint4*)dstL = L;
}

// Split float4 -> bf16 hi ushort4 + lo ushort4 (truncation + residual).
__device__ __forceinline__ void split4(float4 v, ushort4* H, ushort4* L) {
  unsigned ux = __float_as_uint(v.x), uy = __float_as_uint(v.y);
  unsigned uz = __float_as_uint(v.z), uw = __float_as_uint(v.w);
  H->x = (unsigned short)(ux >> 16);
  H->y = (unsigned short)(uy >> 16);
  H->z = (unsigned short)(uz >> 16);
  H->w = (unsigned short)(uw >> 16);
  float rx = v.x - __uint_as_float(ux & 0xFFFF0000u);
  float ry = v.y - __uint_as_float(uy & 0xFFFF0000u);
  float rz = v.z - __uint_as_float(uz & 0xFFFF0000u);
  float rw = v.w - __uint_as_float(uw & 0xFFFF0000u);
  L->x = (unsigned short)(__float_as_uint(rx) >> 16);
  L->y = (unsigned short)(__float_as_uint(ry) >> 16);
  L->z = (unsigned short)(__float_as_uint(rz) >> 16);
  L->w = (unsigned short)(__float_as_uint(rw) >> 16);
}

// Merge helpers for scores partials: lane-major LDS region (64 lanes x 32
// floats), 8 b128 slots per lane, XOR-swizzled (slot ^ lane&7) so the 8
// tx-classes spread across bank quads.
__device__ __forceinline__ void merge_wr(float* buf, int lane,
                                         const float a[4][8]) {
#pragma unroll
  for (int i = 0; i < 4; i++) {
    int s0 = ((2 * i) ^ (lane & 7)) << 2;
    int s1 = ((2 * i + 1) ^ (lane & 7)) << 2;
    float4 v0 = {a[i][0], a[i][1], a[i][2], a[i][3]};
    float4 v1 = {a[i][4], a[i][5], a[i][6], a[i][7]};
    *(float4*)&buf[lane * 32 + s0] = v0;
    *(float4*)&buf[lane * 32 + s1] = v1;
  }
}
__device__ __forceinline__ void merge_rd(const float* buf, int lane,
                                         float a[4][8]) {
#pragma unroll
  for (int i = 0; i < 4; i++) {
    int s0 = ((2 * i) ^ (lane & 7)) << 2;
    int s1 = ((2 * i + 1) ^ (lane & 7)) << 2;
    float4 v0 = *(const float4*)&buf[lane * 32 + s0];
    float4 v1 = *(const float4*)&buf[lane * 32 + s1];
    a[i][0] += v0.x; a[i][1] += v0.y; a[i][2] += v0.z; a[i][3] += v0.w;
    a[i][4] += v1.x; a[i][5] += v1.y; a[i][6] += v1.z; a[i][7] += v1.w;
  }
}

// Fused projections via split-bf16 MFMA (3 mfma: hi*hi + hi*lo + lo*hi).
// ET[b][h][x] = exp2(K2L*(sum_k A[m][k]*W[h][k] + bias[h])), m=b*512+x
// 64(m) x 64(h) tile, K-step 32, grid (64,4,2), block 256 = 4 waves,
// each wave a 32x32 quadrant (2x2 MFMA 16x16x32 frags). Double-buffered
// LDS (1 barrier/step), rows padded to 40 ushort (2-way bank alias, free).
__global__ __launch_bounds__(256) void proj_mfma(
    const float* __restrict__ A0, const float* __restrict__ A1,
    const float* __restrict__ W0, const float* __restrict__ W1,
    const float* __restrict__ bias0, const float* __restrict__ bias1,
    float* __restrict__ E0, float* __restrict__ E1) {
  // [buf][mat: Ah,Al,Wh,Wl][row][k] ; row stride 40 ushort = 80 B (16B mult)
  __shared__ unsigned short lds[2][4][64][40];
  const int K = CD;
  int z = blockIdx.z;
  const float* A = z ? A1 : A0;
  const float* W = z ? W1 : W0;
  const float* bias = z ? bias1 : bias0;
  float* ET = z ? E1 : E0;
  int m0 = blockIdx.x * 64, n0 = blockIdx.y * 64;
  int tid = threadIdx.x;
  int lane = tid & 63, w = tid >> 6;
  int wm = w >> 1, wn = w & 1;  // wave quadrant: m-half, n-half
  // staging: 64 rows x (4 threads/row x 8 k)
  int r = tid >> 2, kq = (tid & 3) * 8;
  const float* pA = A + (size_t)(m0 + r) * K + kq;
  const float* pW = W + (size_t)(n0 + r) * K + kq;
  f32x4 acc[2][2] = {};
  float4 a0 = *(const float4*)(pA);
  float4 a1 = *(const float4*)(pA + 4);
  float4 w0 = *(const float4*)(pW);
  float4 w1 = *(const float4*)(pW + 4);
  cvt_store(&lds[0][0][r][kq], &lds[0][1][r][kq], a0, a1);
  cvt_store(&lds[0][2][r][kq], &lds[0][3][r][kq], w0, w1);
  for (int s = 0; s < 8; s++) {
    __syncthreads();
    if (s < 7) {
      int kt = (s + 1) * 32;
      a0 = *(const float4*)(pA + kt);
      a1 = *(const float4*)(pA + kt + 4);
      w0 = *(const float4*)(pW + kt);
      w1 = *(const float4*)(pW + kt + 4);
    }
    int cur = s & 1;
    int arow = wm * 32 + (lane & 15);
    int brow = wn * 32 + (lane & 15);
    int koff = (lane >> 4) * 8;
    short8 ah0 = *(const short8*)&lds[cur][0][arow][koff];
    short8 ah1 = *(const short8*)&lds[cur][0][arow + 16][koff];
    short8 al0 = *(const short8*)&lds[cur][1][arow][koff];
    short8 al1 = *(const short8*)&lds[cur][1][arow + 16][koff];
    short8 bh0 = *(const short8*)&lds[cur][2][brow][koff];
    short8 bh1 = *(const short8*)&lds[cur][2][brow + 16][koff];
    short8 bl0 = *(const short8*)&lds[cur][3][brow][koff];
    short8 bl1 = *(const short8*)&lds[cur][3][brow + 16][koff];
    acc[0][0] = __builtin_amdgcn_mfma_f32_16x16x32_bf16(ah0, bh0, acc[0][0], 0, 0, 0);
    acc[0][1] = __builtin_amdgcn_mfma_f32_16x16x32_bf16(ah0, bh1, acc[0][1], 0, 0, 0);
    acc[1][0] = __builtin_amdgcn_mfma_f32_16x16x32_bf16(ah1, bh0, acc[1][0], 0, 0, 0);
    acc[1][1] = __builtin_amdgcn_mfma_f32_16x16x32_bf16(ah1, bh1, acc[1][1], 0, 0, 0);
    acc[0][0] = __builtin_amdgcn_mfma_f32_16x16x32_bf16(ah0, bl0, acc[0][0], 0, 0, 0);
    acc[0][1] = __builtin_amdgcn_mfma_f32_16x16x32_bf16(ah0, bl1, acc[0][1], 0, 0, 0);
    acc[1][0] = __builtin_amdgcn_mfma_f32_16x16x32_bf16(ah1, bl0, acc[1][0], 0, 0, 0);
    acc[1][1] = __builtin_amdgcn_mfma_f32_16x16x32_bf16(ah1, bl1, acc[1][1], 0, 0, 0);
    acc[0][0] = __builtin_amdgcn_mfma_f32_16x16x32_bf16(al0, bh0, acc[0][0], 0, 0, 0);
    acc[0][1] = __builtin_amdgcn_mfma_f32_16x16x32_bf16(al0, bh1, acc[0][1], 0, 0, 0);
    acc[1][0] = __builtin_amdgcn_mfma_f32_16x16x32_bf16(al1, bh0, acc[1][0], 0, 0, 0);
    acc[1][1] = __builtin_amdgcn_mfma_f32_16x16x32_bf16(al1, bh1, acc[1][1], 0, 0, 0);
    if (s < 7) {
      int nxt = cur ^ 1;
      cvt_store(&lds[nxt][0][r][kq], &lds[nxt][1][r][kq], a0, a1);
      cvt_store(&lds[nxt][2][r][kq], &lds[nxt][3][r][kq], w0, w1);
    }
  }
  const float K2L = 2.8853900817779268f;  // 2*log2(e)
  int b = m0 >> 9;
  int xq = (m0 & 511) + wm * 32 + (lane >> 4) * 4;
#pragma unroll
  for (int mi = 0; mi < 2; mi++) {
#pragma unroll
    for (int ni = 0; ni < 2; ni++) {
      int h = n0 + wn * 32 + ni * 16 + (lane & 15);
      float bb = bias[h];
      f32x4 a = acc[mi][ni];
      float4 o = {fast_exp2(K2L * (a[0] + bb)), fast_exp2(K2L * (a[1] + bb)),
                  fast_exp2(K2L * (a[2] + bb)), fast_exp2(K2L * (a[3] + bb))};
      *(float4*)(ET + ((size_t)b * CH + h) * CNX + xq + mi * 16) = o;
    }
  }
}

// scT[b][r][x] = -2 * sum_h v_w[h] / (exT[b][h][x]*erT[b][h][r] + 1)
// v5: 64(x) x 32(r) tile, grid (8,16,8)=1024 blocks, block 256 = 4 waves.
// Each wave covers the FULL tile with an 8x4 microtile (32 outputs/lane)
// and owns 1/4 of h (rows g*8..g*8+7 of each staged 32-h chunk).
// Double-buffered staging (1 barrier/chunk), 4h fraction-merge,
// XOR-swizzled LDS partial-merge tree. VGPR <= 128 -> 4 blocks/CU.
__global__ __launch_bounds__(256, 4) void scores_kernel(
    const float* __restrict__ exT, const float* __restrict__ erT,
    const float* __restrict__ v_w, float* __restrict__ scT) {
  // 2 bufs x (xs[32][64] + rs[32][32]) = 6144 floats; vsh[256]
  __shared__ float smem[6144 + 256];
  int b = blockIdx.z;
  int x0 = blockIdx.x * 64, r0 = blockIdx.y * 32;
  int tid = threadIdx.x;
  int lane = tid & 63, g = tid >> 6;
  int tx = lane & 7, ty = lane >> 3;  // tx -> x(8), ty -> r(4)
  float* vsh = smem + 6144;
  vsh[tid] = v_w[tid];
  // staging: xs 32h x 64x (8 floats/thread), rs 32h x 32r (4 floats/thread)
  int srow = tid >> 3, sxc = (tid & 7) * 8, src = (tid & 7) * 4;
  const float* pX = exT + (size_t)b * CH * CNX + x0;
  const float* pR = erT + (size_t)b * CH * CNR + r0;
  float4 px0 = *(const float4*)(pX + (size_t)srow * CNX + sxc);
  float4 px1 = *(const float4*)(pX + (size_t)srow * CNX + sxc + 4);
  float4 pr0 = *(const float4*)(pR + (size_t)srow * CNR + src);
  {
    float* xs = smem;
    float* rs = smem + 2048;
    *(float4*)&xs[srow * 64 + sxc] = px0;
    *(float4*)&xs[srow * 64 + sxc + 4] = px1;
    *(float4*)&rs[srow * 32 + src] = pr0;
  }
  float acc[4][8] = {};
  for (int c = 0; c < 8; c++) {
    __syncthreads();
    if (c < 7) {
      int hn = (c + 1) * 32 + srow;
      px0 = *(const float4*)(pX + (size_t)hn * CNX + sxc);
      px1 = *(const float4*)(pX + (size_t)hn * CNX + sxc + 4);
      pr0 = *(const float4*)(pR + (size_t)hn * CNR + src);
    }
    const float* xs = smem + (c & 1) * 3072;
    const float* rs = xs + 2048;
#pragma unroll
    for (int q = 0; q < 2; q++) {
      int hl = g * 8 + q * 4;  // this wave's rows within the chunk
      float4 vv = *(const float4*)&vsh[c * 32 + hl];
      float xm0[8], xm1[8], xm2[8], xm3[8];
      float rm0[4], rm1[4], rm2[4], rm3[4];
      *(float4*)&xm0[0] = *(const float4*)&xs[(hl + 0) * 64 + tx * 8];
      *(float4*)&xm0[4] = *(const float4*)&xs[(hl + 0) * 64 + tx * 8 + 4];
      *(float4*)&xm1[0] = *(const float4*)&xs[(hl + 1) * 64 + tx * 8];
      *(float4*)&xm1[4] = *(const float4*)&xs[(hl + 1) * 64 + tx * 8 + 4];
      *(float4*)&xm2[0] = *(const float4*)&xs[(hl + 2) * 64 + tx * 8];
      *(float4*)&xm2[4] = *(const float4*)&xs[(hl + 2) * 64 + tx * 8 + 4];
      *(float4*)&xm3[0] = *(const float4*)&xs[(hl + 3) * 64 + tx * 8];
      *(float4*)&xm3[4] = *(const float4*)&xs[(hl + 3) * 64 + tx * 8 + 4];
      *(float4*)&rm0[0] = *(const float4*)&rs[(hl + 0) * 32 + ty * 4];
      *(float4*)&rm1[0] = *(const float4*)&rs[(hl + 1) * 32 + ty * 4];
      *(float4*)&rm2[0] = *(const float4*)&rs[(hl + 2) * 32 + ty * 4];
      *(float4*)&rm3[0] = *(const float4*)&rs[(hl + 3) * 32 + ty * 4];
#pragma unroll
      for (int i = 0; i < 4; i++)
#pragma unroll
        for (int j = 0; j < 8; j++) {
          float a = fmaf(rm0[i], xm0[j], 1.0f);
          float bb = fmaf(rm1[i], xm1[j], 1.0f);
          float cc = fmaf(rm2[i], xm2[j], 1.0f);
          float dd = fmaf(rm3[i], xm3[j], 1.0f);
          float q12 = a * bb, q34 = cc * dd;
          float p12 = fmaf(vv.y, a, vv.x * bb);
          float p34 = fmaf(vv.w, cc, vv.z * dd);
          float num = fmaf(p34, q12, p12 * q34);
          acc[i][j] = fmaf(num, fast_rcp(q12 * q34), acc[i][j]);
        }
    }
    if (c < 7) {
      float* xw = smem + ((c + 1) & 1) * 3072;
      float* rw = xw + 2048;
      *(float4*)&xw[srow * 64 + sxc] = px0;
      *(float4*)&xw[srow * 64 + sxc + 4] = px1;
      *(float4*)&rw[srow * 32 + src] = pr0;
    }
  }
  // merge the 4 h-partials: tree over 2 swizzled 8-KB lane-major regions
  float* bufA = smem;
  float* bufB = smem + 2048;
  __syncthreads();
  if (g == 1) merge_wr(bufA, lane, acc);
  if (g == 3) merge_wr(bufB, lane, acc);
  __syncthreads();
  if (g == 0) merge_rd(bufA, lane, acc);
  if (g == 2) merge_rd(bufB, lane, acc);
  __syncthreads();
  if (g == 2) merge_wr(bufA, lane, acc);
  __syncthreads();
  if (g == 0) {
    merge_rd(bufA, lane, acc);
    float* pO = scT + ((size_t)b * CNR + r0 + ty * 4) * CNX + x0 + tx * 8;
#pragma unroll
    for (int i = 0; i < 4; i++) {
      float4 o0 = {-2.0f * acc[i][0], -2.0f * acc[i][1],
                   -2.0f * acc[i][2], -2.0f * acc[i][3]};
      float4 o1 = {-2.0f * acc[i][4], -2.0f * acc[i][5],
                   -2.0f * acc[i][6], -2.0f * acc[i][7]};
      *(float4*)(pO + (size_t)i * CNX) = o0;
      *(float4*)(pO + (size_t)i * CNX + 4) = o1;
    }
  }
}

// Fused softmax + weighted sum via split-bf16 MFMA.
// out[b][r][d] = sum_x P[r][x]*X[x][d] / sum_x P[r][x], P = exp(scT).
// 64(r) x 64(d) tile, K-step 32(x), grid (8,4,8)=256 blocks, block 512 =
// 8 waves (2 r-halves x 4 d-quarters), 3 mfma per frag-pair (hi*hi +
// hi*lo + lo*hi). LDS rows = [hi(32k) | lo(32k)] bf16 = 128 B with T2
// XOR swizzle (slot ^= row&7) -> conflict-free b128 frag reads.
// X transposed in-register at staging (coalesced loads along d).
__global__ __launch_bounds__(512) void wsum_mfma(
    const float* __restrict__ scT, const float* __restrict__ X,
    float* __restrict__ out) {
  // [buf][mat: P, Xt][row][64 ushort]; row = [hi 32k | lo 32k], 8 slots x 16B
  __shared__ unsigned short lds[2][2][64][64];
  __shared__ float dn[64];
  const float L2E = 1.4426950408889634f;
  int b = blockIdx.z;
  int r0 = blockIdx.x * 64, d0 = blockIdx.y * 64;
  int tid = threadIdx.x;
  int lane = tid & 63, w = tid >> 6;
  int wm = w >> 2, wn = w & 3;  // r-half (32), d-quarter (16)
  // P staging: row pr (64), 4 k per thread
  int pr = tid >> 3, pxk = (tid & 7) * 4;
  int psl = pxk >> 3, pof = pxk & 7;  // slot 0..3, offset 0 or 4
  // X staging: d-row xd (64), 4 x per thread (in-register transpose)
  int xd = tid & 63, xx = (tid >> 6) * 4;
  int xsl = xx >> 3, xof = xx & 7;
  const float* pS = scT + ((size_t)b * CNR + r0 + pr) * CNX + pxk;
  const float* pX = X + ((size_t)b * CNX + xx) * CD + d0 + xd;
  f32x4 acc0 = {}, acc1 = {};
  float dsum = 0.0f;
  float4 sv = *(const float4*)(pS);
  float4 xv = {pX[0], pX[CD], pX[2 * CD], pX[3 * CD]};
  {
    float4 ev = {fast_exp2(sv.x * L2E), fast_exp2(sv.y * L2E),
                 fast_exp2(sv.z * L2E), fast_exp2(sv.w * L2E)};
    dsum += (ev.x + ev.y) + (ev.z + ev.w);
    ushort4 H, L;
    split4(ev, &H, &L);
    unsigned short* rp = &lds[0][0][pr][0];
    *(ushort4*)(rp + ((psl ^ (pr & 7)) << 3) + pof) = H;
    *(ushort4*)(rp + (((psl + 4) ^ (pr & 7)) << 3) + pof) = L;
    split4(xv, &H, &L);
    unsigned short* rx = &lds[0][1][xd][0];
    *(ushort4*)(rx + ((xsl ^ (xd & 7)) << 3) + xof) = H;
    *(ushort4*)(rx + (((xsl + 4) ^ (xd & 7)) << 3) + xof) = L;
  }
  int q = lane >> 4;            // k-slot 0..3
  int mr0 = wm * 32 + (lane & 15);
  int mr1 = mr0 + 16;
  int nr = wn * 16 + (lane & 15);
  for (int s = 0; s < 16; s++) {
    __syncthreads();
    if (s < 15) {
      int kt = (s + 1) * 32;
      sv = *(const float4*)(pS + kt);
      xv.x = pX[(size_t)(kt + 0) * CD];
      xv.y = pX[(size_t)(kt + 1) * CD];
      xv.z = pX[(size_t)(kt + 2) * CD];
      xv.w = pX[(size_t)(kt + 3) * CD];
    }
    int cur = s & 1;
    const unsigned short* Pt = &lds[cur][0][0][0];
    const unsigned short* Xt = &lds[cur][1][0][0];
    short8 ah0 = *(const short8*)(Pt + mr0 * 64 + ((q ^ (mr0 & 7)) << 3));
    short8 al0 = *(const short8*)(Pt + mr0 * 64 + (((q + 4) ^ (mr0 & 7)) << 3));
    short8 ah1 = *(const short8*)(Pt + mr1 * 64 + ((q ^ (mr1 & 7)) << 3));
    short8 al1 = *(const short8*)(Pt + mr1 * 64 + (((q + 4) ^ (mr1 & 7)) << 3));
    short8 bh = *(const short8*)(Xt + nr * 64 + ((q ^ (nr & 7)) << 3));
    short8 bl = *(const short8*)(Xt + nr * 64 + (((q + 4) ^ (nr & 7)) << 3));
    acc0 = __builtin_amdgcn_mfma_f32_16x16x32_bf16(ah0, bh, acc0, 0, 0, 0);
    acc1 = __builtin_amdgcn_mfma_f32_16x16x32_bf16(ah1, bh, acc1, 0, 0, 0);
    acc0 = __builtin_amdgcn_mfma_f32_16x16x32_bf16(ah0, bl, acc0, 0, 0, 0);
    acc1 = __builtin_amdgcn_mfma_f32_16x16x32_bf16(ah1, bl, acc1, 0, 0, 0);
    acc0 = __builtin_amdgcn_mfma_f32_16x16x32_bf16(al0, bh, acc0, 0, 0, 0);
    acc1 = __builtin_amdgcn_mfma_f32_16x16x32_bf16(al1, bh, acc1, 0, 0, 0);
    if (s < 15) {
      int nxt = cur ^ 1;
      float4 ev = {fast_exp2(sv.x * L2E), fast_exp2(sv.y * L2E),
                   fast_exp2(sv.z * L2E), fast_exp2(sv.w * L2E)};
      dsum += (ev.x + ev.y) + (ev.z + ev.w);
      ushort4 H, L;
      split4(ev, &H, &L);
      unsigned short* rp = &lds[nxt][0][pr][0];
      *(ushort4*)(rp + ((psl ^ (pr & 7)) << 3) + pof) = H;
      *(ushort4*)(rp + (((psl + 4) ^ (pr & 7)) << 3) + pof) = L;
      split4(xv, &H, &L);
      unsigned short* rx = &lds[nxt][1][xd][0];
      *(ushort4*)(rx + ((xsl ^ (xd & 7)) << 3) + xof) = H;
      *(ushort4*)(rx + (((xsl + 4) ^ (xd & 7)) << 3) + xof) = L;
    }
  }
  // denominator: 8 threads (tid&7) share row pr
  dsum += __shfl_xor(dsum, 1, 64);
  dsum += __shfl_xor(dsum, 2, 64);
  dsum += __shfl_xor(dsum, 4, 64);
  if ((tid & 7) == 0) dn[pr] = dsum;
  __syncthreads();
  int col = d0 + wn * 16 + (lane & 15);
  float* pO = out + ((size_t)b * CNR + r0) * CD + col;
#pragma unroll
  for (int j = 0; j < 4; j++) {
    int row = wm * 32 + q * 4 + j;
    pO[(size_t)row * CD] = acc0[j] * fast_rcp(dn[row]);
  }
#pragma unroll
  for (int j = 0; j < 4; j++) {
    int row = wm * 32 + 16 + q * 4 + j;
    pO[(size_t)row * CD] = acc1[j] * fast_rcp(dn[row]);
  }
}

extern "C" void kernel_launch(void* const* d_in, const int* in_sizes, int n_in,
                              void* d_out, int out_size, void* d_ws, size_t ws_size,
                              hipStream_t stream) {
  const float* X     = (const float*)d_in[0];
  const float* ref   = (const float*)d_in[1];
  const float* W_X   = (const float*)d_in[2];
  const float* b_X   = (const float*)d_in[3];
  const float* W_ref = (const float*)d_in[4];
  const float* b_ref = (const float*)d_in[5];
  const float* v_w   = (const float*)d_in[6];
  float* out = (float*)d_out;
  float* ws  = (float*)d_ws;

  float* exT = ws;                       // [B][H][NX] = 1,048,576 floats
  float* erT = ws + 1048576;             // [B][H][NR] = 1,048,576 floats
  float* scT = ws + 2097152;             // [B][NR][NX] = 2,097,152 floats

  proj_mfma<<<dim3(64, 4, 2), 256, 0, stream>>>(X, ref, W_X, W_ref, b_X, b_ref, exT, erT);
  scores_kernel<<<dim3(8, 16, 8), 256, 0, stream>>>(exT, erT, v_w, scT);
  wsum_mfma<<<dim3(8, 4, 8), 512, 0, stream>>>(scT, X, out);
}

// Round 8
// 134.523 us; speedup vs baseline: 1.7848x; 1.7848x over previous
//
#include <hip/hip_runtime.h>
#include <math.h>

#define CB 8
#define CNX 512
#define CNR 512
#define CD 256
#define CH 256

typedef __attribute__((ext_vector_type(8))) short short8;
typedef __attribute__((ext_vector_type(4))) float f32x4;

__device__ __forceinline__ float fast_rcp(float x) {
#if __has_builtin(__builtin_amdgcn_rcpf)
  return __builtin_amdgcn_rcpf(x);
#else
  return 1.0f / x;
#endif
}
__device__ __forceinline__ float fast_exp2(float x) {
#if __has_builtin(__builtin_amdgcn_exp2f)
  return __builtin_amdgcn_exp2f(x);
#else
  return exp2f(x);
#endif
}

// Split a float into bf16 hi (truncation) + bf16 lo (residual, truncated),
// packing 8 consecutive k-values into uint4 hi and uint4 lo, store to LDS.
__device__ __forceinline__ void cvt_store(unsigned short* dstH,
                                          unsigned short* dstL,
                                          float4 v0, float4 v1) {
  unsigned u0x = __float_as_uint(v0.x), u0y = __float_as_uint(v0.y);
  unsigned u0z = __float_as_uint(v0.z), u0w = __float_as_uint(v0.w);
  unsigned u1x = __float_as_uint(v1.x), u1y = __float_as_uint(v1.y);
  unsigned u1z = __float_as_uint(v1.z), u1w = __float_as_uint(v1.w);
  uint4 H;
  H.x = (u0x >> 16) | (u0y & 0xFFFF0000u);
  H.y = (u0z >> 16) | (u0w & 0xFFFF0000u);
  H.z = (u1x >> 16) | (u1y & 0xFFFF0000u);
  H.w = (u1z >> 16) | (u1w & 0xFFFF0000u);
  float r0x = v0.x - __uint_as_float(u0x & 0xFFFF0000u);
  float r0y = v0.y - __uint_as_float(u0y & 0xFFFF0000u);
  float r0z = v0.z - __uint_as_float(u0z & 0xFFFF0000u);
  float r0w = v0.w - __uint_as_float(u0w & 0xFFFF0000u);
  float r1x = v1.x - __uint_as_float(u1x & 0xFFFF0000u);
  float r1y = v1.y - __uint_as_float(u1y & 0xFFFF0000u);
  float r1z = v1.z - __uint_as_float(u1z & 0xFFFF0000u);
  float r1w = v1.w - __uint_as_float(u1w & 0xFFFF0000u);
  uint4 L;
  L.x = (__float_as_uint(r0x) >> 16) | (__float_as_uint(r0y) & 0xFFFF0000u);
  L.y = (__float_as_uint(r0z) >> 16) | (__float_as_uint(r0w) & 0xFFFF0000u);
  L.z = (__float_as_uint(r1x) >> 16) | (__float_as_uint(r1y) & 0xFFFF0000u);
  L.w = (__float_as_uint(r1z) >> 16) | (__float_as_uint(r1w) & 0xFFFF0000u);
  *(uint4*)dstH = H;
  *(uint4*)dstL = L;
}

// Split float4 -> bf16 hi ushort4 + lo ushort4 (truncation + residual).
__device__ __forceinline__ void split4(float4 v, ushort4* H, ushort4* L) {
  unsigned ux = __float_as_uint(v.x), uy = __float_as_uint(v.y);
  unsigned uz = __float_as_uint(v.z), uw = __float_as_uint(v.w);
  H->x = (unsigned short)(ux >> 16);
  H->y = (unsigned short)(uy >> 16);
  H->z = (unsigned short)(uz >> 16);
  H->w = (unsigned short)(uw >> 16);
  float rx = v.x - __uint_as_float(ux & 0xFFFF0000u);
  float ry = v.y - __uint_as_float(uy & 0xFFFF0000u);
  float rz = v.z - __uint_as_float(uz & 0xFFFF0000u);
  float rw = v.w - __uint_as_float(uw & 0xFFFF0000u);
  L->x = (unsigned short)(__float_as_uint(rx) >> 16);
  L->y = (unsigned short)(__float_as_uint(ry) >> 16);
  L->z = (unsigned short)(__float_as_uint(rz) >> 16);
  L->w = (unsigned short)(__float_as_uint(rw) >> 16);
}

// Fused projections via split-bf16 MFMA (3 mfma: hi*hi + hi*lo + lo*hi).
// ET[b][h][x] = exp2(K2L*(sum_k A[m][k]*W[h][k] + bias[h])), m=b*512+x
// 64(m) x 64(h) tile, K-step 32, grid (64,4,2), block 256 = 4 waves,
// each wave a 32x32 quadrant (2x2 MFMA 16x16x32 frags). Double-buffered
// LDS (1 barrier/step), rows padded to 40 ushort (2-way bank alias, free).
__global__ __launch_bounds__(256) void proj_mfma(
    const float* __restrict__ A0, const float* __restrict__ A1,
    const float* __restrict__ W0, const float* __restrict__ W1,
    const float* __restrict__ bias0, const float* __restrict__ bias1,
    float* __restrict__ E0, float* __restrict__ E1) {
  // [buf][mat: Ah,Al,Wh,Wl][row][k] ; row stride 40 ushort = 80 B (16B mult)
  __shared__ unsigned short lds[2][4][64][40];
  const int K = CD;
  int z = blockIdx.z;
  const float* A = z ? A1 : A0;
  const float* W = z ? W1 : W0;
  const float* bias = z ? bias1 : bias0;
  float* ET = z ? E1 : E0;
  int m0 = blockIdx.x * 64, n0 = blockIdx.y * 64;
  int tid = threadIdx.x;
  int lane = tid & 63, w = tid >> 6;
  int wm = w >> 1, wn = w & 1;  // wave quadrant: m-half, n-half
  // staging: 64 rows x (4 threads/row x 8 k)
  int r = tid >> 2, kq = (tid & 3) * 8;
  const float* pA = A + (size_t)(m0 + r) * K + kq;
  const float* pW = W + (size_t)(n0 + r) * K + kq;
  f32x4 acc[2][2] = {};
  float4 a0 = *(const float4*)(pA);
  float4 a1 = *(const float4*)(pA + 4);
  float4 w0 = *(const float4*)(pW);
  float4 w1 = *(const float4*)(pW + 4);
  cvt_store(&lds[0][0][r][kq], &lds[0][1][r][kq], a0, a1);
  cvt_store(&lds[0][2][r][kq], &lds[0][3][r][kq], w0, w1);
  for (int s = 0; s < 8; s++) {
    __syncthreads();
    if (s < 7) {
      int kt = (s + 1) * 32;
      a0 = *(const float4*)(pA + kt);
      a1 = *(const float4*)(pA + kt + 4);
      w0 = *(const float4*)(pW + kt);
      w1 = *(const float4*)(pW + kt + 4);
    }
    int cur = s & 1;
    int arow = wm * 32 + (lane & 15);
    int brow = wn * 32 + (lane & 15);
    int koff = (lane >> 4) * 8;
    short8 ah0 = *(const short8*)&lds[cur][0][arow][koff];
    short8 ah1 = *(const short8*)&lds[cur][0][arow + 16][koff];
    short8 al0 = *(const short8*)&lds[cur][1][arow][koff];
    short8 al1 = *(const short8*)&lds[cur][1][arow + 16][koff];
    short8 bh0 = *(const short8*)&lds[cur][2][brow][koff];
    short8 bh1 = *(const short8*)&lds[cur][2][brow + 16][koff];
    short8 bl0 = *(const short8*)&lds[cur][3][brow][koff];
    short8 bl1 = *(const short8*)&lds[cur][3][brow + 16][koff];
    acc[0][0] = __builtin_amdgcn_mfma_f32_16x16x32_bf16(ah0, bh0, acc[0][0], 0, 0, 0);
    acc[0][1] = __builtin_amdgcn_mfma_f32_16x16x32_bf16(ah0, bh1, acc[0][1], 0, 0, 0);
    acc[1][0] = __builtin_amdgcn_mfma_f32_16x16x32_bf16(ah1, bh0, acc[1][0], 0, 0, 0);
    acc[1][1] = __builtin_amdgcn_mfma_f32_16x16x32_bf16(ah1, bh1, acc[1][1], 0, 0, 0);
    acc[0][0] = __builtin_amdgcn_mfma_f32_16x16x32_bf16(ah0, bl0, acc[0][0], 0, 0, 0);
    acc[0][1] = __builtin_amdgcn_mfma_f32_16x16x32_bf16(ah0, bl1, acc[0][1], 0, 0, 0);
    acc[1][0] = __builtin_amdgcn_mfma_f32_16x16x32_bf16(ah1, bl0, acc[1][0], 0, 0, 0);
    acc[1][1] = __builtin_amdgcn_mfma_f32_16x16x32_bf16(ah1, bl1, acc[1][1], 0, 0, 0);
    acc[0][0] = __builtin_amdgcn_mfma_f32_16x16x32_bf16(al0, bh0, acc[0][0], 0, 0, 0);
    acc[0][1] = __builtin_amdgcn_mfma_f32_16x16x32_bf16(al0, bh1, acc[0][1], 0, 0, 0);
    acc[1][0] = __builtin_amdgcn_mfma_f32_16x16x32_bf16(al1, bh0, acc[1][0], 0, 0, 0);
    acc[1][1] = __builtin_amdgcn_mfma_f32_16x16x32_bf16(al1, bh1, acc[1][1], 0, 0, 0);
    if (s < 7) {
      int nxt = cur ^ 1;
      cvt_store(&lds[nxt][0][r][kq], &lds[nxt][1][r][kq], a0, a1);
      cvt_store(&lds[nxt][2][r][kq], &lds[nxt][3][r][kq], w0, w1);
    }
  }
  const float K2L = 2.8853900817779268f;  // 2*log2(e)
  int b = m0 >> 9;
  int xq = (m0 & 511) + wm * 32 + (lane >> 4) * 4;
#pragma unroll
  for (int mi = 0; mi < 2; mi++) {
#pragma unroll
    for (int ni = 0; ni < 2; ni++) {
      int h = n0 + wn * 32 + ni * 16 + (lane & 15);
      float bb = bias[h];
      f32x4 a = acc[mi][ni];
      float4 o = {fast_exp2(K2L * (a[0] + bb)), fast_exp2(K2L * (a[1] + bb)),
                  fast_exp2(K2L * (a[2] + bb)), fast_exp2(K2L * (a[3] + bb))};
      *(float4*)(ET + ((size_t)b * CH + h) * CNX + xq + mi * 16) = o;
    }
  }
}

// One 4-h fraction-merge term: acc += (v-weighted numerator)/(product).
// All operands are named scalars / vector components (spill-safe).
#define STERM(R0, R1, R2, R3, X0, X1, X2, X3, A)     \
  do {                                               \
    float ta = fmaf(R0, X0, 1.0f);                   \
    float tb = fmaf(R1, X1, 1.0f);                   \
    float tc = fmaf(R2, X2, 1.0f);                   \
    float td = fmaf(R3, X3, 1.0f);                   \
    float q12 = ta * tb, q34 = tc * td;              \
    float p12 = fmaf(vv.y, ta, vv.x * tb);           \
    float p34 = fmaf(vv.w, tc, vv.z * td);           \
    float num = fmaf(p34, q12, p12 * q34);           \
    A = fmaf(num, fast_rcp(q12 * q34), A);           \
  } while (0)

#define SROW(I, R0, R1, R2, R3)                                          \
  do {                                                                   \
    STERM(R0, R1, R2, R3, x0a.x, x1a.x, x2a.x, x3a.x, acc[I][0]);        \
    STERM(R0, R1, R2, R3, x0a.y, x1a.y, x2a.y, x3a.y, acc[I][1]);        \
    STERM(R0, R1, R2, R3, x0a.z, x1a.z, x2a.z, x3a.z, acc[I][2]);        \
    STERM(R0, R1, R2, R3, x0a.w, x1a.w, x2a.w, x3a.w, acc[I][3]);        \
    STERM(R0, R1, R2, R3, x0b.x, x1b.x, x2b.x, x3b.x, acc[I][4]);        \
    STERM(R0, R1, R2, R3, x0b.y, x1b.y, x2b.y, x3b.y, acc[I][5]);        \
    STERM(R0, R1, R2, R3, x0b.z, x1b.z, x2b.z, x3b.z, acc[I][6]);        \
    STERM(R0, R1, R2, R3, x0b.w, x1b.w, x2b.w, x3b.w, acc[I][7]);        \
  } while (0)

// scT[b][r][x] = -2 * sum_h v_w[h] / (exT[b][h][x]*erT[b][h][r] + 1)
// v6 (v5 rebuilt spill-safe): 64(x) x 32(r) tile, grid (8,16,8)=1024
// blocks (4/CU), block 256 = 4 waves. Each wave covers the full tile with
// an 8x4 microtile (32 outputs/lane, acc[4][8] constant-indexed) and owns
// 1/4 of h (8 rows per staged 32-h chunk). Double-buffered staging, one
// barrier per chunk; frags held only in named float4s loaded directly
// from LDS; scalar lane-major partial merge (2 lanes/bank, no conflicts).
__global__ __launch_bounds__(256) void scores_kernel(
    const float* __restrict__ exT, const float* __restrict__ erT,
    const float* __restrict__ v_w, float* __restrict__ scT) {
  // 2 bufs x (xs[32][68] + rs[32][40]) = 6912 floats + vsh[256]
  __shared__ float smem[6912 + 256];
  int b = blockIdx.z;
  int x0 = blockIdx.x * 64, r0 = blockIdx.y * 32;
  int tid = threadIdx.x;
  int lane = tid & 63, g = tid >> 6;
  int tx = lane & 7, ty = lane >> 3;  // tx -> x(8), ty -> r(4)
  float* vsh = smem + 6912;
  vsh[tid] = v_w[tid];
  // staging: 32 rows; xs 8 floats/thread, rs 4 floats/thread
  int srow = tid >> 3, sxc = (tid & 7) * 8, src = (tid & 7) * 4;
  const float* pX = exT + (size_t)b * CH * CNX + x0;
  const float* pR = erT + (size_t)b * CH * CNR + r0;
  float4 xa0 = *(const float4*)(pX + (size_t)srow * CNX + sxc);
  float4 xa1 = *(const float4*)(pX + (size_t)srow * CNX + sxc + 4);
  float4 ra0 = *(const float4*)(pR + (size_t)srow * CNR + src);
  {
    float* xs = smem;
    float* rs = smem + 2176;
    *(float4*)&xs[srow * 68 + sxc] = xa0;
    *(float4*)&xs[srow * 68 + sxc + 4] = xa1;
    *(float4*)&rs[srow * 40 + src] = ra0;
  }
  float acc[4][8] = {};
  for (int c = 0; c < 8; c++) {
    __syncthreads();
    if (c < 7) {
      int hn = (c + 1) * 32 + srow;
      xa0 = *(const float4*)(pX + (size_t)hn * CNX + sxc);
      xa1 = *(const float4*)(pX + (size_t)hn * CNX + sxc + 4);
      ra0 = *(const float4*)(pR + (size_t)hn * CNR + src);
    }
    const float* xs = smem + (c & 1) * 3456;
    const float* rs = xs + 2176;
#pragma unroll
    for (int q = 0; q < 2; q++) {
      int hl = g * 8 + q * 4;  // this wave's rows within the chunk
      float4 vv = *(const float4*)&vsh[c * 32 + hl];
      float4 x0a = *(const float4*)&xs[(hl + 0) * 68 + tx * 8];
      float4 x0b = *(const float4*)&xs[(hl + 0) * 68 + tx * 8 + 4];
      float4 x1a = *(const float4*)&xs[(hl + 1) * 68 + tx * 8];
      float4 x1b = *(const float4*)&xs[(hl + 1) * 68 + tx * 8 + 4];
      float4 x2a = *(const float4*)&xs[(hl + 2) * 68 + tx * 8];
      float4 x2b = *(const float4*)&xs[(hl + 2) * 68 + tx * 8 + 4];
      float4 x3a = *(const float4*)&xs[(hl + 3) * 68 + tx * 8];
      float4 x3b = *(const float4*)&xs[(hl + 3) * 68 + tx * 8 + 4];
      float4 rv0 = *(const float4*)&rs[(hl + 0) * 40 + ty * 4];
      float4 rv1 = *(const float4*)&rs[(hl + 1) * 40 + ty * 4];
      float4 rv2 = *(const float4*)&rs[(hl + 2) * 40 + ty * 4];
      float4 rv3 = *(const float4*)&rs[(hl + 3) * 40 + ty * 4];
      SROW(0, rv0.x, rv1.x, rv2.x, rv3.x);
      SROW(1, rv0.y, rv1.y, rv2.y, rv3.y);
      SROW(2, rv0.z, rv1.z, rv2.z, rv3.z);
      SROW(3, rv0.w, rv1.w, rv2.w, rv3.w);
    }
    if (c < 7) {
      float* xw = smem + ((c + 1) & 1) * 3456;
      float* rw = xw + 2176;
      *(float4*)&xw[srow * 68 + sxc] = xa0;
      *(float4*)&xw[srow * 68 + sxc + 4] = xa1;
      *(float4*)&rw[srow * 40 + src] = ra0;
    }
  }
  // scalar lane-major merge of the 4 h-partials (reuse smem after barrier)
  float* mgA = smem;
  float* mgB = smem + 2048;
  __syncthreads();
  if (g == 1) {
#pragma unroll
    for (int s = 0; s < 32; s++) mgA[s * 64 + lane] = acc[s >> 3][s & 7];
  }
  if (g == 3) {
#pragma unroll
    for (int s = 0; s < 32; s++) mgB[s * 64 + lane] = acc[s >> 3][s & 7];
  }
  __syncthreads();
  if (g == 0) {
#pragma unroll
    for (int s = 0; s < 32; s++) acc[s >> 3][s & 7] += mgA[s * 64 + lane];
  }
  if (g == 2) {
#pragma unroll
    for (int s = 0; s < 32; s++) acc[s >> 3][s & 7] += mgB[s * 64 + lane];
  }
  __syncthreads();
  if (g == 2) {
#pragma unroll
    for (int s = 0; s < 32; s++) mgA[s * 64 + lane] = acc[s >> 3][s & 7];
  }
  __syncthreads();
  if (g == 0) {
#pragma unroll
    for (int s = 0; s < 32; s++) acc[s >> 3][s & 7] += mgA[s * 64 + lane];
    float* pO = scT + ((size_t)b * CNR + r0 + ty * 4) * CNX + x0 + tx * 8;
#pragma unroll
    for (int i = 0; i < 4; i++) {
      float4 o0 = {-2.0f * acc[i][0], -2.0f * acc[i][1],
                   -2.0f * acc[i][2], -2.0f * acc[i][3]};
      float4 o1 = {-2.0f * acc[i][4], -2.0f * acc[i][5],
                   -2.0f * acc[i][6], -2.0f * acc[i][7]};
      *(float4*)(pO + (size_t)i * CNX) = o0;
      *(float4*)(pO + (size_t)i * CNX + 4) = o1;
    }
  }
}

// Fused softmax + weighted sum via split-bf16 MFMA.
// out[b][r][d] = sum_x P[r][x]*X[x][d] / sum_x P[r][x], P = exp(scT).
// 64(r) x 64(d) tile, K-step 32(x), grid (8,4,8)=256 blocks, block 512 =
// 8 waves (2 r-halves x 4 d-quarters), 3 mfma per frag-pair (hi*hi +
// hi*lo + lo*hi). LDS rows = [hi(32k) | lo(32k)] bf16 = 128 B with T2
// XOR swizzle (slot ^= row&7) -> conflict-free b128 frag reads.
// X transposed in-register at staging (coalesced loads along d).
__global__ __launch_bounds__(512) void wsum_mfma(
    const float* __restrict__ scT, const float* __restrict__ X,
    float* __restrict__ out) {
  // [buf][mat: P, Xt][row][64 ushort]; row = [hi 32k | lo 32k], 8 slots x 16B
  __shared__ unsigned short lds[2][2][64][64];
  __shared__ float dn[64];
  const float L2E = 1.4426950408889634f;
  int b = blockIdx.z;
  int r0 = blockIdx.x * 64, d0 = blockIdx.y * 64;
  int tid = threadIdx.x;
  int lane = tid & 63, w = tid >> 6;
  int wm = w >> 2, wn = w & 3;  // r-half (32), d-quarter (16)
  // P staging: row pr (64), 4 k per thread
  int pr = tid >> 3, pxk = (tid & 7) * 4;
  int psl = pxk >> 3, pof = pxk & 7;  // slot 0..3, offset 0 or 4
  // X staging: d-row xd (64), 4 x per thread (in-register transpose)
  int xd = tid & 63, xx = (tid >> 6) * 4;
  int xsl = xx >> 3, xof = xx & 7;
  const float* pS = scT + ((size_t)b * CNR + r0 + pr) * CNX + pxk;
  const float* pX = X + ((size_t)b * CNX + xx) * CD + d0 + xd;
  f32x4 acc0 = {}, acc1 = {};
  float dsum = 0.0f;
  float4 sv = *(const float4*)(pS);
  float4 xv = {pX[0], pX[CD], pX[2 * CD], pX[3 * CD]};
  {
    float4 ev = {fast_exp2(sv.x * L2E), fast_exp2(sv.y * L2E),
                 fast_exp2(sv.z * L2E), fast_exp2(sv.w * L2E)};
    dsum += (ev.x + ev.y) + (ev.z + ev.w);
    ushort4 H, L;
    split4(ev, &H, &L);
    unsigned short* rp = &lds[0][0][pr][0];
    *(ushort4*)(rp + ((psl ^ (pr & 7)) << 3) + pof) = H;
    *(ushort4*)(rp + (((psl + 4) ^ (pr & 7)) << 3) + pof) = L;
    split4(xv, &H, &L);
    unsigned short* rx = &lds[0][1][xd][0];
    *(ushort4*)(rx + ((xsl ^ (xd & 7)) << 3) + xof) = H;
    *(ushort4*)(rx + (((xsl + 4) ^ (xd & 7)) << 3) + xof) = L;
  }
  int q = lane >> 4;            // k-slot 0..3
  int mr0 = wm * 32 + (lane & 15);
  int mr1 = mr0 + 16;
  int nr = wn * 16 + (lane & 15);
  for (int s = 0; s < 16; s++) {
    __syncthreads();
    if (s < 15) {
      int kt = (s + 1) * 32;
      sv = *(const float4*)(pS + kt);
      xv.x = pX[(size_t)(kt + 0) * CD];
      xv.y = pX[(size_t)(kt + 1) * CD];
      xv.z = pX[(size_t)(kt + 2) * CD];
      xv.w = pX[(size_t)(kt + 3) * CD];
    }
    int cur = s & 1;
    const unsigned short* Pt = &lds[cur][0][0][0];
    const unsigned short* Xt = &lds[cur][1][0][0];
    short8 ah0 = *(const short8*)(Pt + mr0 * 64 + ((q ^ (mr0 & 7)) << 3));
    short8 al0 = *(const short8*)(Pt + mr0 * 64 + (((q + 4) ^ (mr0 & 7)) << 3));
    short8 ah1 = *(const short8*)(Pt + mr1 * 64 + ((q ^ (mr1 & 7)) << 3));
    short8 al1 = *(const short8*)(Pt + mr1 * 64 + (((q + 4) ^ (mr1 & 7)) << 3));
    short8 bh = *(const short8*)(Xt + nr * 64 + ((q ^ (nr & 7)) << 3));
    short8 bl = *(const short8*)(Xt + nr * 64 + (((q + 4) ^ (nr & 7)) << 3));
    acc0 = __builtin_amdgcn_mfma_f32_16x16x32_bf16(ah0, bh, acc0, 0, 0, 0);
    acc1 = __builtin_amdgcn_mfma_f32_16x16x32_bf16(ah1, bh, acc1, 0, 0, 0);
    acc0 = __builtin_amdgcn_mfma_f32_16x16x32_bf16(ah0, bl, acc0, 0, 0, 0);
    acc1 = __builtin_amdgcn_mfma_f32_16x16x32_bf16(ah1, bl, acc1, 0, 0, 0);
    acc0 = __builtin_amdgcn_mfma_f32_16x16x32_bf16(al0, bh, acc0, 0, 0, 0);
    acc1 = __builtin_amdgcn_mfma_f32_16x16x32_bf16(al1, bh, acc1, 0, 0, 0);
    if (s < 15) {
      int nxt = cur ^ 1;
      float4 ev = {fast_exp2(sv.x * L2E), fast_exp2(sv.y * L2E),
                   fast_exp2(sv.z * L2E), fast_exp2(sv.w * L2E)};
      dsum += (ev.x + ev.y) + (ev.z + ev.w);
      ushort4 H, L;
      split4(ev, &H, &L);
      unsigned short* rp = &lds[nxt][0][pr][0];
      *(ushort4*)(rp + ((psl ^ (pr & 7)) << 3) + pof) = H;
      *(ushort4*)(rp + (((psl + 4) ^ (pr & 7)) << 3) + pof) = L;
      split4(xv, &H, &L);
      unsigned short* rx = &lds[nxt][1][xd][0];
      *(ushort4*)(rx + ((xsl ^ (xd & 7)) << 3) + xof) = H;
      *(ushort4*)(rx + (((xsl + 4) ^ (xd & 7)) << 3) + xof) = L;
    }
  }
  // denominator: 8 threads (tid&7) share row pr
  dsum += __shfl_xor(dsum, 1, 64);
  dsum += __shfl_xor(dsum, 2, 64);
  dsum += __shfl_xor(dsum, 4, 64);
  if ((tid & 7) == 0) dn[pr] = dsum;
  __syncthreads();
  int col = d0 + wn * 16 + (lane & 15);
  float* pO = out + ((size_t)b * CNR + r0) * CD + col;
#pragma unroll
  for (int j = 0; j < 4; j++) {
    int row = wm * 32 + q * 4 + j;
    pO[(size_t)row * CD] = acc0[j] * fast_rcp(dn[row]);
  }
#pragma unroll
  for (int j = 0; j < 4; j++) {
    int row = wm * 32 + 16 + q * 4 + j;
    pO[(size_t)row * CD] = acc1[j] * fast_rcp(dn[row]);
  }
}

extern "C" void kernel_launch(void* const* d_in, const int* in_sizes, int n_in,
                              void* d_out, int out_size, void* d_ws, size_t ws_size,
                              hipStream_t stream) {
  const float* X     = (const float*)d_in[0];
  const float* ref   = (const float*)d_in[1];
  const float* W_X   = (const float*)d_in[2];
  const float* b_X   = (const float*)d_in[3];
  const float* W_ref = (const float*)d_in[4];
  const float* b_ref = (const float*)d_in[5];
  const float* v_w   = (const float*)d_in[6];
  float* out = (float*)d_out;
  float* ws  = (float*)d_ws;

  float* exT = ws;                       // [B][H][NX] = 1,048,576 floats
  float* erT = ws + 1048576;             // [B][H][NR] = 1,048,576 floats
  float* scT = ws + 2097152;             // [B][NR][NX] = 2,097,152 floats

  proj_mfma<<<dim3(64, 4, 2), 256, 0, stream>>>(X, ref, W_X, W_ref, b_X, b_ref, exT, erT);
  scores_kernel<<<dim3(8, 16, 8), 256, 0, stream>>>(exT, erT, v_w, scT);
  wsum_mfma<<<dim3(8, 4, 8), 512, 0, stream>>>(scT, X, out);
}

// Round 9
// 133.256 us; speedup vs baseline: 1.8017x; 1.0095x over previous
//
#include <hip/hip_runtime.h>
#include <math.h>

#define CB 8
#define CNX 512
#define CNR 512
#define CD 256
#define CH 256

typedef __attribute__((ext_vector_type(8))) short short8;
typedef __attribute__((ext_vector_type(4))) float f32x4;

__device__ __forceinline__ float fast_rcp(float x) {
#if __has_builtin(__builtin_amdgcn_rcpf)
  return __builtin_amdgcn_rcpf(x);
#else
  return 1.0f / x;
#endif
}
__device__ __forceinline__ float fast_exp2(float x) {
#if __has_builtin(__builtin_amdgcn_exp2f)
  return __builtin_amdgcn_exp2f(x);
#else
  return exp2f(x);
#endif
}

// Split a float into bf16 hi (truncation) + bf16 lo (residual, truncated),
// packing 8 consecutive k-values into uint4 hi and uint4 lo, store to LDS.
__device__ __forceinline__ void cvt_store(unsigned short* dstH,
                                          unsigned short* dstL,
                                          float4 v0, float4 v1) {
  unsigned u0x = __float_as_uint(v0.x), u0y = __float_as_uint(v0.y);
  unsigned u0z = __float_as_uint(v0.z), u0w = __float_as_uint(v0.w);
  unsigned u1x = __float_as_uint(v1.x), u1y = __float_as_uint(v1.y);
  unsigned u1z = __float_as_uint(v1.z), u1w = __float_as_uint(v1.w);
  uint4 H;
  H.x = (u0x >> 16) | (u0y & 0xFFFF0000u);
  H.y = (u0z >> 16) | (u0w & 0xFFFF0000u);
  H.z = (u1x >> 16) | (u1y & 0xFFFF0000u);
  H.w = (u1z >> 16) | (u1w & 0xFFFF0000u);
  float r0x = v0.x - __uint_as_float(u0x & 0xFFFF0000u);
  float r0y = v0.y - __uint_as_float(u0y & 0xFFFF0000u);
  float r0z = v0.z - __uint_as_float(u0z & 0xFFFF0000u);
  float r0w = v0.w - __uint_as_float(u0w & 0xFFFF0000u);
  float r1x = v1.x - __uint_as_float(u1x & 0xFFFF0000u);
  float r1y = v1.y - __uint_as_float(u1y & 0xFFFF0000u);
  float r1z = v1.z - __uint_as_float(u1z & 0xFFFF0000u);
  float r1w = v1.w - __uint_as_float(u1w & 0xFFFF0000u);
  uint4 L;
  L.x = (__float_as_uint(r0x) >> 16) | (__float_as_uint(r0y) & 0xFFFF0000u);
  L.y = (__float_as_uint(r0z) >> 16) | (__float_as_uint(r0w) & 0xFFFF0000u);
  L.z = (__float_as_uint(r1x) >> 16) | (__float_as_uint(r1y) & 0xFFFF0000u);
  L.w = (__float_as_uint(r1z) >> 16) | (__float_as_uint(r1w) & 0xFFFF0000u);
  *(uint4*)dstH = H;
  *(uint4*)dstL = L;
}

// Split float4 -> bf16 hi ushort4 + lo ushort4 (truncation + residual).
__device__ __forceinline__ void split4(float4 v, ushort4* H, ushort4* L) {
  unsigned ux = __float_as_uint(v.x), uy = __float_as_uint(v.y);
  unsigned uz = __float_as_uint(v.z), uw = __float_as_uint(v.w);
  H->x = (unsigned short)(ux >> 16);
  H->y = (unsigned short)(uy >> 16);
  H->z = (unsigned short)(uz >> 16);
  H->w = (unsigned short)(uw >> 16);
  float rx = v.x - __uint_as_float(ux & 0xFFFF0000u);
  float ry = v.y - __uint_as_float(uy & 0xFFFF0000u);
  float rz = v.z - __uint_as_float(uz & 0xFFFF0000u);
  float rw = v.w - __uint_as_float(uw & 0xFFFF0000u);
  L->x = (unsigned short)(__float_as_uint(rx) >> 16);
  L->y = (unsigned short)(__float_as_uint(ry) >> 16);
  L->z = (unsigned short)(__float_as_uint(rz) >> 16);
  L->w = (unsigned short)(__float_as_uint(rw) >> 16);
}

// Fused projections via split-bf16 MFMA (3 mfma: hi*hi + hi*lo + lo*hi).
// ET[b][h][x] = exp2(K2L*(sum_k A[m][k]*W[h][k] + bias[h])), m=b*512+x
// 64(m) x 64(h) tile, K-step 32, grid (64,4,2), block 256 = 4 waves,
// each wave a 32x32 quadrant (2x2 MFMA 16x16x32 frags). Double-buffered
// LDS (1 barrier/step), rows padded to 40 ushort (2-way bank alias, free).
__global__ __launch_bounds__(256) void proj_mfma(
    const float* __restrict__ A0, const float* __restrict__ A1,
    const float* __restrict__ W0, const float* __restrict__ W1,
    const float* __restrict__ bias0, const float* __restrict__ bias1,
    float* __restrict__ E0, float* __restrict__ E1) {
  // [buf][mat: Ah,Al,Wh,Wl][row][k] ; row stride 40 ushort = 80 B (16B mult)
  __shared__ unsigned short lds[2][4][64][40];
  const int K = CD;
  int z = blockIdx.z;
  const float* A = z ? A1 : A0;
  const float* W = z ? W1 : W0;
  const float* bias = z ? bias1 : bias0;
  float* ET = z ? E1 : E0;
  int m0 = blockIdx.x * 64, n0 = blockIdx.y * 64;
  int tid = threadIdx.x;
  int lane = tid & 63, w = tid >> 6;
  int wm = w >> 1, wn = w & 1;  // wave quadrant: m-half, n-half
  // staging: 64 rows x (4 threads/row x 8 k)
  int r = tid >> 2, kq = (tid & 3) * 8;
  const float* pA = A + (size_t)(m0 + r) * K + kq;
  const float* pW = W + (size_t)(n0 + r) * K + kq;
  f32x4 acc[2][2] = {};
  float4 a0 = *(const float4*)(pA);
  float4 a1 = *(const float4*)(pA + 4);
  float4 w0 = *(const float4*)(pW);
  float4 w1 = *(const float4*)(pW + 4);
  cvt_store(&lds[0][0][r][kq], &lds[0][1][r][kq], a0, a1);
  cvt_store(&lds[0][2][r][kq], &lds[0][3][r][kq], w0, w1);
  for (int s = 0; s < 8; s++) {
    __syncthreads();
    if (s < 7) {
      int kt = (s + 1) * 32;
      a0 = *(const float4*)(pA + kt);
      a1 = *(const float4*)(pA + kt + 4);
      w0 = *(const float4*)(pW + kt);
      w1 = *(const float4*)(pW + kt + 4);
    }
    int cur = s & 1;
    int arow = wm * 32 + (lane & 15);
    int brow = wn * 32 + (lane & 15);
    int koff = (lane >> 4) * 8;
    short8 ah0 = *(const short8*)&lds[cur][0][arow][koff];
    short8 ah1 = *(const short8*)&lds[cur][0][arow + 16][koff];
    short8 al0 = *(const short8*)&lds[cur][1][arow][koff];
    short8 al1 = *(const short8*)&lds[cur][1][arow + 16][koff];
    short8 bh0 = *(const short8*)&lds[cur][2][brow][koff];
    short8 bh1 = *(const short8*)&lds[cur][2][brow + 16][koff];
    short8 bl0 = *(const short8*)&lds[cur][3][brow][koff];
    short8 bl1 = *(const short8*)&lds[cur][3][brow + 16][koff];
    acc[0][0] = __builtin_amdgcn_mfma_f32_16x16x32_bf16(ah0, bh0, acc[0][0], 0, 0, 0);
    acc[0][1] = __builtin_amdgcn_mfma_f32_16x16x32_bf16(ah0, bh1, acc[0][1], 0, 0, 0);
    acc[1][0] = __builtin_amdgcn_mfma_f32_16x16x32_bf16(ah1, bh0, acc[1][0], 0, 0, 0);
    acc[1][1] = __builtin_amdgcn_mfma_f32_16x16x32_bf16(ah1, bh1, acc[1][1], 0, 0, 0);
    acc[0][0] = __builtin_amdgcn_mfma_f32_16x16x32_bf16(ah0, bl0, acc[0][0], 0, 0, 0);
    acc[0][1] = __builtin_amdgcn_mfma_f32_16x16x32_bf16(ah0, bl1, acc[0][1], 0, 0, 0);
    acc[1][0] = __builtin_amdgcn_mfma_f32_16x16x32_bf16(ah1, bl0, acc[1][0], 0, 0, 0);
    acc[1][1] = __builtin_amdgcn_mfma_f32_16x16x32_bf16(ah1, bl1, acc[1][1], 0, 0, 0);
    acc[0][0] = __builtin_amdgcn_mfma_f32_16x16x32_bf16(al0, bh0, acc[0][0], 0, 0, 0);
    acc[0][1] = __builtin_amdgcn_mfma_f32_16x16x32_bf16(al0, bh1, acc[0][1], 0, 0, 0);
    acc[1][0] = __builtin_amdgcn_mfma_f32_16x16x32_bf16(al1, bh0, acc[1][0], 0, 0, 0);
    acc[1][1] = __builtin_amdgcn_mfma_f32_16x16x32_bf16(al1, bh1, acc[1][1], 0, 0, 0);
    if (s < 7) {
      int nxt = cur ^ 1;
      cvt_store(&lds[nxt][0][r][kq], &lds[nxt][1][r][kq], a0, a1);
      cvt_store(&lds[nxt][2][r][kq], &lds[nxt][3][r][kq], w0, w1);
    }
  }
  const float K2L = 2.8853900817779268f;  // 2*log2(e)
  int b = m0 >> 9;
  int xq = (m0 & 511) + wm * 32 + (lane >> 4) * 4;
#pragma unroll
  for (int mi = 0; mi < 2; mi++) {
#pragma unroll
    for (int ni = 0; ni < 2; ni++) {
      int h = n0 + wn * 32 + ni * 16 + (lane & 15);
      float bb = bias[h];
      f32x4 a = acc[mi][ni];
      float4 o = {fast_exp2(K2L * (a[0] + bb)), fast_exp2(K2L * (a[1] + bb)),
                  fast_exp2(K2L * (a[2] + bb)), fast_exp2(K2L * (a[3] + bb))};
      *(float4*)(ET + ((size_t)b * CH + h) * CNX + xq + mi * 16) = o;
    }
  }
}

// scT[b][r][x] = -2 * sum_h v_w[h] / (exT[b][h][x]*erT[b][h][r] + 1)
// v4 (proven 51.4us): 64(x) x 64(r) tile, grid (8,8,8)=512 blocks, block
// 512 (two 256-thread groups h-splitting the reduction), 4x4 microtile,
// LDS partial-merge, per-wave hq-rotation.
__global__ __launch_bounds__(512) void scores_kernel(
    const float* __restrict__ exT, const float* __restrict__ erT,
    const float* __restrict__ v_w, float* __restrict__ scT) {
  // layout: xs0[32*64] rs0[32*64] xs1[32*64] rs1[32*64] vsh[256]
  __shared__ float smem[4 * 2048 + 256];
  int b = blockIdx.z;
  int x0 = blockIdx.x * 64, r0 = blockIdx.y * 64;
  int tid = threadIdx.x;
  int g = tid >> 8;      // reduction group
  int t = tid & 255;
  float* xs = smem + g * 4096;   // [32][64]
  float* rs = xs + 2048;         // [32][64]
  float* vsh = smem + 8192;
  if (tid < 256) vsh[tid] = v_w[tid];
  int tx = t & 15, ty = t >> 4;  // tx -> x(4), ty -> r(4)
  int sr = t >> 4, sc = (t & 15) * 4;  // staging: 16 rows x 16 float4
  int wrot = (tid >> 6) & 7;     // 8 waves -> rotate hq by 0..7
  const float* pX = exT + (size_t)b * CH * CNX + x0 + sc;
  const float* pR = erT + (size_t)b * CH * CNR + r0 + sc;
  int hb = g * 32;
  float4 xa0 = *(const float4*)(pX + (size_t)(hb + sr) * CNX);
  float4 xa1 = *(const float4*)(pX + (size_t)(hb + sr + 16) * CNX);
  float4 ra0 = *(const float4*)(pR + (size_t)(hb + sr) * CNR);
  float4 ra1 = *(const float4*)(pR + (size_t)(hb + sr + 16) * CNR);
  float acc[4][4] = {};
  for (int hc = hb; hc < CH; hc += 64) {
    __syncthreads();
    *(float4*)&xs[sr * 64 + sc] = xa0;
    *(float4*)&xs[(sr + 16) * 64 + sc] = xa1;
    *(float4*)&rs[sr * 64 + sc] = ra0;
    *(float4*)&rs[(sr + 16) * 64 + sc] = ra1;
    __syncthreads();
    if (hc + 64 < CH) {
      xa0 = *(const float4*)(pX + (size_t)(hc + 64 + sr) * CNX);
      xa1 = *(const float4*)(pX + (size_t)(hc + 64 + sr + 16) * CNX);
      ra0 = *(const float4*)(pR + (size_t)(hc + 64 + sr) * CNR);
      ra1 = *(const float4*)(pR + (size_t)(hc + 64 + sr + 16) * CNR);
    }
#pragma unroll 2
    for (int hq = 0; hq < 8; hq++) {
      int h0 = ((hq + wrot) & 7) * 4;
      float4 vv = *(const float4*)&vsh[hc + h0];
      float4 xv0 = *(const float4*)&xs[(h0 + 0) * 64 + tx * 4];
      float4 xv1 = *(const float4*)&xs[(h0 + 1) * 64 + tx * 4];
      float4 xv2 = *(const float4*)&xs[(h0 + 2) * 64 + tx * 4];
      float4 xv3 = *(const float4*)&xs[(h0 + 3) * 64 + tx * 4];
      float4 rv0 = *(const float4*)&rs[(h0 + 0) * 64 + ty * 4];
      float4 rv1 = *(const float4*)&rs[(h0 + 1) * 64 + ty * 4];
      float4 rv2 = *(const float4*)&rs[(h0 + 2) * 64 + ty * 4];
      float4 rv3 = *(const float4*)&rs[(h0 + 3) * 64 + ty * 4];
      float xm0[4] = {xv0.x, xv0.y, xv0.z, xv0.w};
      float xm1[4] = {xv1.x, xv1.y, xv1.z, xv1.w};
      float xm2[4] = {xv2.x, xv2.y, xv2.z, xv2.w};
      float xm3[4] = {xv3.x, xv3.y, xv3.z, xv3.w};
      float rm0[4] = {rv0.x, rv0.y, rv0.z, rv0.w};
      float rm1[4] = {rv1.x, rv1.y, rv1.z, rv1.w};
      float rm2[4] = {rv2.x, rv2.y, rv2.z, rv2.w};
      float rm3[4] = {rv3.x, rv3.y, rv3.z, rv3.w};
#pragma unroll
      for (int i = 0; i < 4; i++)
#pragma unroll
        for (int j = 0; j < 4; j++) {
          float a = fmaf(rm0[i], xm0[j], 1.0f);
          float bb = fmaf(rm1[i], xm1[j], 1.0f);
          float c = fmaf(rm2[i], xm2[j], 1.0f);
          float d = fmaf(rm3[i], xm3[j], 1.0f);
          float q12 = a * bb, q34 = c * d;
          float p12 = fmaf(vv.y, a, vv.x * bb);
          float p34 = fmaf(vv.w, c, vv.z * d);
          float num = fmaf(p34, q12, p12 * q34);
          acc[i][j] = fmaf(num, fast_rcp(q12 * q34), acc[i][j]);
        }
    }
  }
  // merge the two h-partials (reuse smem[0..4096) after barrier)
  __syncthreads();
  float* mg = smem;
  if (g == 1) {
#pragma unroll
    for (int i = 0; i < 4; i++)
#pragma unroll
      for (int j = 0; j < 4; j++)
        mg[t + 256 * (i * 4 + j)] = acc[i][j];
  }
  __syncthreads();
  if (g == 0) {
    float* pO = scT + ((size_t)b * CNR + r0 + ty * 4) * CNX + x0 + tx * 4;
#pragma unroll
    for (int i = 0; i < 4; i++) {
      float4 o = {-2.0f * (acc[i][0] + mg[t + 256 * (i * 4 + 0)]),
                  -2.0f * (acc[i][1] + mg[t + 256 * (i * 4 + 1)]),
                  -2.0f * (acc[i][2] + mg[t + 256 * (i * 4 + 2)]),
                  -2.0f * (acc[i][3] + mg[t + 256 * (i * 4 + 3)])};
      *(float4*)(pO + (size_t)i * CNX) = o;
    }
  }
}

// Fused softmax + weighted sum via split-bf16 MFMA.
// out[b][r][d] = sum_x P[r][x]*X[x][d] / sum_x P[r][x], P = exp(scT).
// v2: 32(r) x 64(d) tile, grid (16,4,8)=512 blocks (2 blocks/CU -> two
// independent barrier domains overlap), block 256 = 4 waves, each wave
// 32r x 16d (2 acc frags), K-step 32(x), 3 mfma per frag-pair.
// LDS rows = [hi(32k) | lo(32k)] bf16 with XOR swizzle (slot ^= row&7).
__global__ __launch_bounds__(256) void wsum_mfma(
    const float* __restrict__ scT, const float* __restrict__ X,
    float* __restrict__ out) {
  // [buf][(P:32 + Xt:64) rows][64 ushort]
  __shared__ unsigned short lds[2][96][64];
  __shared__ float dn[32];
  const float L2E = 1.4426950408889634f;
  int b = blockIdx.z;
  int r0 = blockIdx.x * 32, d0 = blockIdx.y * 64;
  int tid = threadIdx.x;
  int lane = tid & 63, wn = tid >> 6;  // wn = d-quarter (16)
  // P staging: row pr (32), 4 k per thread (8 threads/row)
  int pr = tid >> 3, pxk = (tid & 7) * 4;
  int psl = pxk >> 3, pof = pxk & 7;  // slot 0..3, offset 0 or 4
  // X staging: d-row xd (64), 8 x per thread = one full 8-wide slot
  int xd = tid & 63, xslot = tid >> 6;           // slot 0..3, x = xslot*8..+7
  const float* pS = scT + ((size_t)b * CNR + r0 + pr) * CNX + pxk;
  const float* pX = X + (size_t)b * CNX * CD + d0 + xd;
  f32x4 acc0 = {}, acc1 = {};
  float dsum = 0.0f;
  float4 sv = *(const float4*)(pS);
  int xb = xslot * 8;
  float4 xvA = {pX[(size_t)(xb + 0) * CD], pX[(size_t)(xb + 1) * CD],
                pX[(size_t)(xb + 2) * CD], pX[(size_t)(xb + 3) * CD]};
  float4 xvB = {pX[(size_t)(xb + 4) * CD], pX[(size_t)(xb + 5) * CD],
                pX[(size_t)(xb + 6) * CD], pX[(size_t)(xb + 7) * CD]};
  {
    float4 ev = {fast_exp2(sv.x * L2E), fast_exp2(sv.y * L2E),
                 fast_exp2(sv.z * L2E), fast_exp2(sv.w * L2E)};
    dsum += (ev.x + ev.y) + (ev.z + ev.w);
    ushort4 H, L;
    split4(ev, &H, &L);
    unsigned short* rp = &lds[0][pr][0];
    *(ushort4*)(rp + ((psl ^ (pr & 7)) << 3) + pof) = H;
    *(ushort4*)(rp + (((psl + 4) ^ (pr & 7)) << 3) + pof) = L;
    ushort4 HA, LA, HB, LB;
    split4(xvA, &HA, &LA);
    split4(xvB, &HB, &LB);
    unsigned short* rx = &lds[0][32 + xd][0];
    *(ushort4*)(rx + ((xslot ^ (xd & 7)) << 3)) = HA;
    *(ushort4*)(rx + ((xslot ^ (xd & 7)) << 3) + 4) = HB;
    *(ushort4*)(rx + (((xslot + 4) ^ (xd & 7)) << 3)) = LA;
    *(ushort4*)(rx + (((xslot + 4) ^ (xd & 7)) << 3) + 4) = LB;
  }
  int q = lane >> 4;            // k-slot 0..3
  int mr0 = lane & 15;          // P rows 0..15
  int mr1 = mr0 + 16;           // P rows 16..31
  int nr = wn * 16 + (lane & 15);  // X d-row
  for (int s = 0; s < 16; s++) {
    __syncthreads();
    if (s < 15) {
      int kt = (s + 1) * 32;
      sv = *(const float4*)(pS + kt);
      xvA.x = pX[(size_t)(kt + xb + 0) * CD];
      xvA.y = pX[(size_t)(kt + xb + 1) * CD];
      xvA.z = pX[(size_t)(kt + xb + 2) * CD];
      xvA.w = pX[(size_t)(kt + xb + 3) * CD];
      xvB.x = pX[(size_t)(kt + xb + 4) * CD];
      xvB.y = pX[(size_t)(kt + xb + 5) * CD];
      xvB.z = pX[(size_t)(kt + xb + 6) * CD];
      xvB.w = pX[(size_t)(kt + xb + 7) * CD];
    }
    int cur = s & 1;
    const unsigned short* Pt = &lds[cur][0][0];
    const unsigned short* Xt = &lds[cur][32][0];
    short8 ah0 = *(const short8*)(Pt + mr0 * 64 + ((q ^ (mr0 & 7)) << 3));
    short8 al0 = *(const short8*)(Pt + mr0 * 64 + (((q + 4) ^ (mr0 & 7)) << 3));
    short8 ah1 = *(const short8*)(Pt + mr1 * 64 + ((q ^ (mr1 & 7)) << 3));
    short8 al1 = *(const short8*)(Pt + mr1 * 64 + (((q + 4) ^ (mr1 & 7)) << 3));
    short8 bh = *(const short8*)(Xt + nr * 64 + ((q ^ (nr & 7)) << 3));
    short8 bl = *(const short8*)(Xt + nr * 64 + (((q + 4) ^ (nr & 7)) << 3));
    acc0 = __builtin_amdgcn_mfma_f32_16x16x32_bf16(ah0, bh, acc0, 0, 0, 0);
    acc1 = __builtin_amdgcn_mfma_f32_16x16x32_bf16(ah1, bh, acc1, 0, 0, 0);
    acc0 = __builtin_amdgcn_mfma_f32_16x16x32_bf16(ah0, bl, acc0, 0, 0, 0);
    acc1 = __builtin_amdgcn_mfma_f32_16x16x32_bf16(ah1, bl, acc1, 0, 0, 0);
    acc0 = __builtin_amdgcn_mfma_f32_16x16x32_bf16(al0, bh, acc0, 0, 0, 0);
    acc1 = __builtin_amdgcn_mfma_f32_16x16x32_bf16(al1, bh, acc1, 0, 0, 0);
    if (s < 15) {
      int nxt = cur ^ 1;
      float4 ev = {fast_exp2(sv.x * L2E), fast_exp2(sv.y * L2E),
                   fast_exp2(sv.z * L2E), fast_exp2(sv.w * L2E)};
      dsum += (ev.x + ev.y) + (ev.z + ev.w);
      ushort4 H, L;
      split4(ev, &H, &L);
      unsigned short* rp = &lds[nxt][pr][0];
      *(ushort4*)(rp + ((psl ^ (pr & 7)) << 3) + pof) = H;
      *(ushort4*)(rp + (((psl + 4) ^ (pr & 7)) << 3) + pof) = L;
      ushort4 HA, LA, HB, LB;
      split4(xvA, &HA, &LA);
      split4(xvB, &HB, &LB);
      unsigned short* rx = &lds[nxt][32 + xd][0];
      *(ushort4*)(rx + ((xslot ^ (xd & 7)) << 3)) = HA;
      *(ushort4*)(rx + ((xslot ^ (xd & 7)) << 3) + 4) = HB;
      *(ushort4*)(rx + (((xslot + 4) ^ (xd & 7)) << 3)) = LA;
      *(ushort4*)(rx + (((xslot + 4) ^ (xd & 7)) << 3) + 4) = LB;
    }
  }
  // denominator: 8 threads (tid&7) share row pr
  dsum += __shfl_xor(dsum, 1, 64);
  dsum += __shfl_xor(dsum, 2, 64);
  dsum += __shfl_xor(dsum, 4, 64);
  if ((tid & 7) == 0) dn[pr] = dsum;
  __syncthreads();
  int col = d0 + wn * 16 + (lane & 15);
  float* pO = out + ((size_t)b * CNR + r0) * CD + col;
#pragma unroll
  for (int j = 0; j < 4; j++) {
    int row = q * 4 + j;
    pO[(size_t)row * CD] = acc0[j] * fast_rcp(dn[row]);
  }
#pragma unroll
  for (int j = 0; j < 4; j++) {
    int row = 16 + q * 4 + j;
    pO[(size_t)row * CD] = acc1[j] * fast_rcp(dn[row]);
  }
}

extern "C" void kernel_launch(void* const* d_in, const int* in_sizes, int n_in,
                              void* d_out, int out_size, void* d_ws, size_t ws_size,
                              hipStream_t stream) {
  const float* X     = (const float*)d_in[0];
  const float* ref   = (const float*)d_in[1];
  const float* W_X   = (const float*)d_in[2];
  const float* b_X   = (const float*)d_in[3];
  const float* W_ref = (const float*)d_in[4];
  const float* b_ref = (const float*)d_in[5];
  const float* v_w   = (const float*)d_in[6];
  float* out = (float*)d_out;
  float* ws  = (float*)d_ws;

  float* exT = ws;                       // [B][H][NX] = 1,048,576 floats
  float* erT = ws + 1048576;             // [B][H][NR] = 1,048,576 floats
  float* scT = ws + 2097152;             // [B][NR][NX] = 2,097,152 floats

  proj_mfma<<<dim3(64, 4, 2), 256, 0, stream>>>(X, ref, W_X, W_ref, b_X, b_ref, exT, erT);
  scores_kernel<<<dim3(8, 8, 8), 512, 0, stream>>>(exT, erT, v_w, scT);
  wsum_mfma<<<dim3(16, 4, 8), 256, 0, stream>>>(scT, X, out);
}